// Round 6
// baseline (503.486 us; speedup 1.0000x reference)
//
#include <hip/hip_runtime.h>
#include <hip/hip_bf16.h>
#include <hip/hip_fp16.h>
#include <math.h>

#define D 128
#define H 4

typedef __attribute__((ext_vector_type(8))) short bf16x8;
typedef __attribute__((ext_vector_type(4))) float f32x4;

// ---------------------------------------------------------------------------
// fp32 -> bf16 split helpers
// ---------------------------------------------------------------------------
__device__ __forceinline__ unsigned short f32_to_bf16_rne(float f) {
    union { float f; unsigned u; } c; c.f = f;
    unsigned u = c.u;
    return (unsigned short)((u + 0x7FFFu + ((u >> 16) & 1u)) >> 16);
}
__device__ __forceinline__ float bf16_to_f32(unsigned short h) {
    union { unsigned u; float f; } c; c.u = ((unsigned)h) << 16;
    return c.f;
}

// ---------------------------------------------------------------------------
// Split fp32 array into bf16 hi + bf16 residual(lo). float4-vectorized.
// ---------------------------------------------------------------------------
__global__ __launch_bounds__(256) void convert_split(
    const float* __restrict__ in, unsigned short* __restrict__ hi,
    unsigned short* __restrict__ lo, int n4)
{
    int i = blockIdx.x * blockDim.x + threadIdx.x;
    if (i >= n4) return;
    float4 v = ((const float4*)in)[i];
    ushort4 h, l;
    h.x = f32_to_bf16_rne(v.x); l.x = f32_to_bf16_rne(v.x - bf16_to_f32(h.x));
    h.y = f32_to_bf16_rne(v.y); l.y = f32_to_bf16_rne(v.y - bf16_to_f32(h.y));
    h.z = f32_to_bf16_rne(v.z); l.z = f32_to_bf16_rne(v.z - bf16_to_f32(h.z));
    h.w = f32_to_bf16_rne(v.w); l.w = f32_to_bf16_rne(v.w - bf16_to_f32(h.w));
    ((ushort4*)hi)[i] = h;
    ((ushort4*)lo)[i] = l;
}

// Split the four 128x128 weight matrices into one packed hi/lo pair.
__global__ __launch_bounds__(256) void convert_w(
    const float* __restrict__ Wq, const float* __restrict__ Wk,
    const float* __restrict__ Wv, const float* __restrict__ Wo,
    unsigned short* __restrict__ wh, unsigned short* __restrict__ wl)
{
    int i = blockIdx.x * blockDim.x + threadIdx.x;
    if (i >= D * D) return;
    const float* Ws[4] = {Wq, Wk, Wv, Wo};
#pragma unroll
    for (int m = 0; m < 4; ++m) {
        float f = Ws[m][i];
        unsigned short h = f32_to_bf16_rne(f);
        wh[m * D * D + i] = h;
        wl[m * D * D + i] = f32_to_bf16_rne(f - bf16_to_f32(h));
    }
}

// ===========================================================================
// Split-precision MFMA GEMM, register-resident W, NO LDS / NO barriers.
//   out[m,c] = (sum_k x[m,k]*W[c,k] + b[c]) * scale
// Block = 512 thr (8 waves); wave `wid` owns col strip [wid*16, wid*16+16):
// its B fragments (hi+lo, 4 K-chunks) live in 32 VGPRs, loaded once (L2/L3).
// Block processes exactly 32 rows: each wave computes 2 independent 16x16
// tiles (2 interleaved MFMA chains for ILP). One-shot grid -> massive TLP
// hides all memory latency; A-loads shared across the block's waves via L1.
// sel = blockIdx.y picks weight/bias/out; halfmask bit -> fp16 output.
// ===========================================================================
__global__ __launch_bounds__(512) void gemm_reg(
    const unsigned short* __restrict__ xh, const unsigned short* __restrict__ xl,
    const unsigned short* __restrict__ whAll, const unsigned short* __restrict__ wlAll,
    const float* __restrict__ b0, const float* __restrict__ b1,
    const float* __restrict__ b2,
    void* __restrict__ o0, void* __restrict__ o1, void* __restrict__ o2,
    float scale0, int n, int wbase, int halfmask)
{
    const int sel = blockIdx.y;
    const unsigned short* wh = whAll + (size_t)(wbase + sel) * D * D;
    const unsigned short* wl = wlAll + (size_t)(wbase + sel) * D * D;
    const float* bias = (sel == 0) ? b0 : (sel == 1 ? b1 : b2);
    void* out        = (sel == 0) ? o0 : (sel == 1 ? o1 : o2);
    const float scale = (sel == 0) ? scale0 : 1.0f;
    const bool halfOut = (halfmask >> sel) & 1;

    const int wid  = threadIdx.x >> 6;   // col strip
    const int lane = threadIdx.x & 63;
    const int quad = lane >> 4;
    const int l16  = lane & 15;

    // ---- B fragments in registers (once) ----
    const unsigned short* wrh = wh + (size_t)(wid * 16 + l16) * D + quad * 8;
    const unsigned short* wrl = wl + (size_t)(wid * 16 + l16) * D + quad * 8;
    bf16x8 bh[4], bl[4];
#pragma unroll
    for (int kc = 0; kc < 4; ++kc) {
        bh[kc] = *(const bf16x8*)(wrh + kc * 32);
        bl[kc] = *(const bf16x8*)(wrl + kc * 32);
    }

    // ---- A fragments: 2 tiles of 16 rows ----
    const int m0 = blockIdx.x * 32;
    int r0 = m0 + l16;      if (r0 > n - 1) r0 = n - 1;
    int r1 = m0 + 16 + l16; if (r1 > n - 1) r1 = n - 1;
    const unsigned short* p0h = xh + (size_t)r0 * D + quad * 8;
    const unsigned short* p0l = xl + (size_t)r0 * D + quad * 8;
    const unsigned short* p1h = xh + (size_t)r1 * D + quad * 8;
    const unsigned short* p1l = xl + (size_t)r1 * D + quad * 8;
    bf16x8 a0h[4], a0l[4], a1h[4], a1l[4];
#pragma unroll
    for (int kc = 0; kc < 4; ++kc) {
        a0h[kc] = *(const bf16x8*)(p0h + kc * 32);
        a0l[kc] = *(const bf16x8*)(p0l + kc * 32);
        a1h[kc] = *(const bf16x8*)(p1h + kc * 32);
        a1l[kc] = *(const bf16x8*)(p1l + kc * 32);
    }

    // ---- 2 interleaved MFMA chains ----
    f32x4 acc0 = {0.f, 0.f, 0.f, 0.f};
    f32x4 acc1 = {0.f, 0.f, 0.f, 0.f};
#pragma unroll
    for (int kc = 0; kc < 4; ++kc) {
        acc0 = __builtin_amdgcn_mfma_f32_16x16x32_bf16(a0h[kc], bh[kc], acc0, 0, 0, 0);
        acc1 = __builtin_amdgcn_mfma_f32_16x16x32_bf16(a1h[kc], bh[kc], acc1, 0, 0, 0);
        acc0 = __builtin_amdgcn_mfma_f32_16x16x32_bf16(a0l[kc], bh[kc], acc0, 0, 0, 0);
        acc1 = __builtin_amdgcn_mfma_f32_16x16x32_bf16(a1l[kc], bh[kc], acc1, 0, 0, 0);
        acc0 = __builtin_amdgcn_mfma_f32_16x16x32_bf16(a0h[kc], bl[kc], acc0, 0, 0, 0);
        acc1 = __builtin_amdgcn_mfma_f32_16x16x32_bf16(a1h[kc], bl[kc], acc1, 0, 0, 0);
    }

    // ---- epilogue ----
    const int colg = wid * 16 + l16;
    const float bv = bias[colg];
    if (halfOut) {
        __half* oph = (__half*)out;
#pragma unroll
        for (int r = 0; r < 4; ++r) {
            int rowg = m0 + quad * 4 + r;
            if (rowg < n) oph[(size_t)rowg * D + colg] = __float2half(acc0[r] + bv);
            rowg += 16;
            if (rowg < n) oph[(size_t)rowg * D + colg] = __float2half(acc1[r] + bv);
        }
    } else {
        float* opf = (float*)out;
#pragma unroll
        for (int r = 0; r < 4; ++r) {
            int rowg = m0 + quad * 4 + r;
            if (rowg < n) opf[(size_t)rowg * D + colg] = (acc0[r] + bv) * scale;
            rowg += 16;
            if (rowg < n) opf[(size_t)rowg * D + colg] = (acc1[r] + bv) * scale;
        }
    }
}

// ---------------------------------------------------------------------------
// row_start[i] = first edge index e with row[e] >= i  (row is sorted)
// ---------------------------------------------------------------------------
__global__ void build_row_start(const int* __restrict__ row,
                                int* __restrict__ row_start, int n, int e)
{
    int i = blockIdx.x * blockDim.x + threadIdx.x;
    if (i > n) return;
    int lo = 0, hi = e;
    while (lo < hi) {
        int mid = (lo + hi) >> 1;
        if (row[mid] < i) lo = mid + 1; else hi = mid;
    }
    row_start[i] = lo;
}

// ===========================================================================
// Fused edge phase: SDDMM + segment-softmax + SPMM, one WAVE per node.
// k, v read as fp16; y written directly as bf16 hi/lo split.
// ===========================================================================
#define MAXDEG 64
#define WPB 4

__global__ __launch_bounds__(WPB * 64) void edge_attn(
    const int* __restrict__ row_start,
    const float* __restrict__ q, const __half* __restrict__ k,
    const __half* __restrict__ v, const int* __restrict__ col,
    unsigned short* __restrict__ yh, unsigned short* __restrict__ yl, int n)
{
    __shared__ float ssm[WPB][MAXDEG * H];
    __shared__ int   cm[WPB][MAXDEG];

    const int wid  = threadIdx.x >> 6;
    const int lane = threadIdx.x & 63;
    const int node = blockIdx.x * WPB + wid;
    if (node >= n) return;

    const int e0  = row_start[node];
    const int deg = row_start[node + 1] - e0;
    const int h   = lane & 3;
    const int dl  = deg < MAXDEG ? deg : MAXDEG;

    const float qa = q[(size_t)node * D + lane];
    const float qb = q[(size_t)node * D + lane + 64];

    for (int i = lane; i < dl; i += 64) cm[wid][i] = col[e0 + i];

    float m = -INFINITY, z = 0.f;
    __half kA = __float2half(0.f), kB = kA;
    if (deg > 0) {
        int c0 = cm[wid][0];
        kA = k[(size_t)c0 * D + lane];
        kB = k[(size_t)c0 * D + lane + 64];
    }
    for (int e = 0; e < deg; ++e) {
        float cA = __half2float(kA), cB = __half2float(kB);
        if (e + 1 < deg) {
            int cn = (e + 1 < MAXDEG) ? cm[wid][e + 1] : col[e0 + e + 1];
            kA = k[(size_t)cn * D + lane];
            kB = k[(size_t)cn * D + lane + 64];
        }
        float p = qa * cA + qb * cB;
        p += __shfl_xor(p, 4);
        p += __shfl_xor(p, 8);
        p += __shfl_xor(p, 16);
        p += __shfl_xor(p, 32);
        if (e < MAXDEG && lane < H) ssm[wid][e * 4 + lane] = p;
        float mn = fmaxf(m, p);
        z = z * __expf(m - mn) + __expf(p - mn);
        m = mn;
    }

    const float rz = 1.f / z;
    const int dl4 = dl * 4;
    for (int f = lane; f < dl4; f += 64)
        ssm[wid][f] = __expf(ssm[wid][f] - m) * rz;

    float acc0 = 0.f, acc1 = 0.f;
    int e = 0;
    for (; e + 4 <= dl; e += 4) {
        int c0 = cm[wid][e], c1 = cm[wid][e + 1];
        int c2 = cm[wid][e + 2], c3 = cm[wid][e + 3];
        float a0 = ssm[wid][e * 4 + h],       a1 = ssm[wid][(e + 1) * 4 + h];
        float a2 = ssm[wid][(e + 2) * 4 + h], a3 = ssm[wid][(e + 3) * 4 + h];
        const __half* v0 = v + (size_t)c0 * D;
        const __half* v1 = v + (size_t)c1 * D;
        const __half* v2 = v + (size_t)c2 * D;
        const __half* v3 = v + (size_t)c3 * D;
        float p00 = __half2float(v0[lane]),      p10 = __half2float(v1[lane]);
        float p20 = __half2float(v2[lane]),      p30 = __half2float(v3[lane]);
        float p01 = __half2float(v0[lane + 64]), p11 = __half2float(v1[lane + 64]);
        float p21 = __half2float(v2[lane + 64]), p31 = __half2float(v3[lane + 64]);
        acc0 += a0 * p00 + a1 * p10 + a2 * p20 + a3 * p30;
        acc1 += a0 * p01 + a1 * p11 + a2 * p21 + a3 * p31;
    }
    for (; e < dl; ++e) {
        int c = cm[wid][e];
        float a = ssm[wid][e * 4 + h];
        acc0 += a * __half2float(v[(size_t)c * D + lane]);
        acc1 += a * __half2float(v[(size_t)c * D + lane + 64]);
    }
    for (int e2 = MAXDEG; e2 < deg; ++e2) {
        int c = col[e0 + e2];
        const __half* kr = k + (size_t)c * D;
        float p = qa * __half2float(kr[lane]) + qb * __half2float(kr[lane + 64]);
        p += __shfl_xor(p, 4);
        p += __shfl_xor(p, 8);
        p += __shfl_xor(p, 16);
        p += __shfl_xor(p, 32);
        float a = __expf(p - m) * rz;
        acc0 += a * __half2float(v[(size_t)c * D + lane]);
        acc1 += a * __half2float(v[(size_t)c * D + lane + 64]);
    }

    unsigned short h0 = f32_to_bf16_rne(acc0);
    unsigned short h1 = f32_to_bf16_rne(acc1);
    yh[(size_t)node * D + lane]      = h0;
    yh[(size_t)node * D + lane + 64] = h1;
    yl[(size_t)node * D + lane]      = f32_to_bf16_rne(acc0 - bf16_to_f32(h0));
    yl[(size_t)node * D + lane + 64] = f32_to_bf16_rne(acc1 - bf16_to_f32(h1));
}

// ---------------------------------------------------------------------------
extern "C" void kernel_launch(void* const* d_in, const int* in_sizes, int n_in,
                              void* d_out, int out_size, void* d_ws, size_t ws_size,
                              hipStream_t stream)
{
    const float* x   = (const float*)d_in[0];
    const int*   row = (const int*)  d_in[1];
    const int*   col = (const int*)  d_in[2];
    const float* Wq  = (const float*)d_in[3];
    const float* bq  = (const float*)d_in[4];
    const float* Wk  = (const float*)d_in[5];
    const float* bk  = (const float*)d_in[6];
    const float* Wv  = (const float*)d_in[7];
    const float* bv  = (const float*)d_in[8];
    const float* Wo  = (const float*)d_in[9];
    const float* bo  = (const float*)d_in[10];
    float* out = (float*)d_out;

    const int n = in_sizes[0] / D;   // 100000
    const int e = in_sizes[1];       // 800000
    const size_t ND = (size_t)n * D;

    // Workspace (floats as unit):
    //   [0,    ND)   q  fp32
    //   [ND,  1.5ND) kh fp16
    //   [1.5ND,2ND)  vh fp16
    //   [2ND, 2.5ND) xh bf16   (aliased: yh after QKV phase)
    //   [2.5ND,3ND)  xl bf16   (aliased: yl)
    //   [3ND, ...)   wh, wl (4*D*D shorts each), row_start
    float* ws = (float*)d_ws;
    float*  q  = ws;
    __half* kh = (__half*)(ws + ND);
    __half* vh = kh + ND;
    unsigned short* xh = (unsigned short*)(ws + 2 * ND);
    unsigned short* xl = xh + ND;
    unsigned short* yh = xh;   // alias (x split dead after QKV GEMM)
    unsigned short* yl = xl;
    unsigned short* wh = (unsigned short*)(ws + 3 * ND);
    unsigned short* wl = wh + 4 * D * D;
    int* row_start = (int*)(wl + 4 * D * D);

    const int n4 = (int)(ND / 4);
    const int gx = (n + 31) / 32;    // 3125

    convert_w<<<(D * D + 255) / 256, 256, 0, stream>>>(Wq, Wk, Wv, Wo, wh, wl);
    convert_split<<<(n4 + 255) / 256, 256, 0, stream>>>(x, xh, xl, n4);

    // fused QKV: sel 0 -> q fp32 (*0.5), sel 1 -> k fp16, sel 2 -> v fp16
    gemm_reg<<<dim3(gx, 3), 512, 0, stream>>>(
        xh, xl, wh, wl, bq, bk, bv,
        (void*)q, (void*)kh, (void*)vh, 0.5f, n, 0, /*halfmask=*/6);

    build_row_start<<<(n + 1 + 255) / 256, 256, 0, stream>>>(row, row_start, n, e);

    edge_attn<<<(n + WPB - 1) / WPB, WPB * 64, 0, stream>>>(
        row_start, q, kh, vh, col, yh, yl, n);

    // output projection: weight slot 3 (Wo), fp32 out
    gemm_reg<<<dim3(gx, 1), 512, 0, stream>>>(
        yh, yl, wh, wl, bo, bo, bo,
        (void*)out, (void*)out, (void*)out, 1.0f, n, 3, /*halfmask=*/0);
}

// Round 7
// 321.122 us; speedup vs baseline: 1.5679x; 1.5679x over previous
//
#include <hip/hip_runtime.h>
#include <hip/hip_bf16.h>
#include <hip/hip_fp16.h>
#include <math.h>

#define D 128
#define H 4

typedef __attribute__((ext_vector_type(8))) short bf16x8;
typedef __attribute__((ext_vector_type(4))) float f32x4;

// ---------------------------------------------------------------------------
// fp32 -> bf16 split helpers
// ---------------------------------------------------------------------------
__device__ __forceinline__ unsigned short f32_to_bf16_rne(float f) {
    union { float f; unsigned u; } c; c.f = f;
    unsigned u = c.u;
    return (unsigned short)((u + 0x7FFFu + ((u >> 16) & 1u)) >> 16);
}
__device__ __forceinline__ float bf16_to_f32(unsigned short h) {
    union { unsigned u; float f; } c; c.u = ((unsigned)h) << 16;
    return c.f;
}

// ---------------------------------------------------------------------------
// Split fp32 array into bf16 hi + bf16 residual(lo). float4-vectorized.
// ---------------------------------------------------------------------------
__global__ __launch_bounds__(256) void convert_split(
    const float* __restrict__ in, unsigned short* __restrict__ hi,
    unsigned short* __restrict__ lo, int n4)
{
    int i = blockIdx.x * blockDim.x + threadIdx.x;
    if (i >= n4) return;
    float4 v = ((const float4*)in)[i];
    ushort4 h, l;
    h.x = f32_to_bf16_rne(v.x); l.x = f32_to_bf16_rne(v.x - bf16_to_f32(h.x));
    h.y = f32_to_bf16_rne(v.y); l.y = f32_to_bf16_rne(v.y - bf16_to_f32(h.y));
    h.z = f32_to_bf16_rne(v.z); l.z = f32_to_bf16_rne(v.z - bf16_to_f32(h.z));
    h.w = f32_to_bf16_rne(v.w); l.w = f32_to_bf16_rne(v.w - bf16_to_f32(h.w));
    ((ushort4*)hi)[i] = h;
    ((ushort4*)lo)[i] = l;
}

// Split the four 128x128 weight matrices into one packed hi/lo pair.
__global__ __launch_bounds__(256) void convert_w(
    const float* __restrict__ Wq, const float* __restrict__ Wk,
    const float* __restrict__ Wv, const float* __restrict__ Wo,
    unsigned short* __restrict__ wh, unsigned short* __restrict__ wl)
{
    int i = blockIdx.x * blockDim.x + threadIdx.x;
    if (i >= D * D) return;
    const float* Ws[4] = {Wq, Wk, Wv, Wo};
#pragma unroll
    for (int m = 0; m < 4; ++m) {
        float f = Ws[m][i];
        unsigned short h = f32_to_bf16_rne(f);
        wh[m * D * D + i] = h;
        wl[m * D * D + i] = f32_to_bf16_rne(f - bf16_to_f32(h));
    }
}

// ===========================================================================
// Split-precision MFMA GEMM:  out[m,c] = (sum_k x[m,k]*W[c,k] + b[c]) * scale
// Block = 512 thr (8 waves), 64-row x 128-col output tile.
//  - A tile (64 rows, hi+lo) staged ONCE into 32 KB LDS with XOR-chunk
//    swizzle (R5-verified zero bank conflicts), coalesced global loads.
//  - B strip (16 cols per wave, hi+lo, 4 K-chunks) in 32 VGPRs, loaded once.
//  - Each wave: 4 independent 16x16 acc chains (ILP) x 4 K-chunks x 3 MFMA
//    (xh*wh + xl*wh + xh*wl -> ~fp32 accuracy).
// sel = blockIdx.y picks weight/bias/out; halfmask bit -> fp16 output.
// ===========================================================================
#define RT 64   // rows per block

__global__ __launch_bounds__(512) void gemm_tile(
    const unsigned short* __restrict__ xh, const unsigned short* __restrict__ xl,
    const unsigned short* __restrict__ whAll, const unsigned short* __restrict__ wlAll,
    const float* __restrict__ b0, const float* __restrict__ b1,
    const float* __restrict__ b2,
    void* __restrict__ o0, void* __restrict__ o1, void* __restrict__ o2,
    float scale0, int n, int wbase, int halfmask)
{
    __shared__ unsigned short Ah[RT * 128];   // 16 KB
    __shared__ unsigned short Al[RT * 128];   // 16 KB

    const int sel = blockIdx.y;
    const unsigned short* wh = whAll + (size_t)(wbase + sel) * D * D;
    const unsigned short* wl = wlAll + (size_t)(wbase + sel) * D * D;
    const float* bias = (sel == 0) ? b0 : (sel == 1 ? b1 : b2);
    void* out        = (sel == 0) ? o0 : (sel == 1 ? o1 : o2);
    const float scale = (sel == 0) ? scale0 : 1.0f;
    const bool halfOut = (halfmask >> sel) & 1;

    const int wid  = threadIdx.x >> 6;   // col strip [16*wid, 16*wid+16)
    const int lane = threadIdx.x & 63;
    const int quad = lane >> 4;
    const int l16  = lane & 15;
    const int m0   = blockIdx.x * RT;

    // ---- B fragments in registers (once; W hot in L1/L2) ----
    const unsigned short* wrh = wh + (size_t)(wid * 16 + l16) * D + quad * 8;
    const unsigned short* wrl = wl + (size_t)(wid * 16 + l16) * D + quad * 8;
    bf16x8 bh[4], bl[4];
#pragma unroll
    for (int kc = 0; kc < 4; ++kc) {
        bh[kc] = *(const bf16x8*)(wrh + kc * 32);
        bl[kc] = *(const bf16x8*)(wrl + kc * 32);
    }

    // ---- stage A tile (hi+lo) into LDS, XOR-swizzled 8-short chunks ----
    for (int idx = threadIdx.x; idx < RT * 16; idx += 512) {
        int r  = idx >> 4;
        int c8 = idx & 15;
        int rg = m0 + r; if (rg > n - 1) rg = n - 1;
        int cs = ((c8 ^ (r & 15)) * 8);
        *(bf16x8*)&Ah[r * 128 + cs] = *(const bf16x8*)(xh + (size_t)rg * D + c8 * 8);
        *(bf16x8*)&Al[r * 128 + cs] = *(const bf16x8*)(xl + (size_t)rg * D + c8 * 8);
    }
    __syncthreads();

    // ---- main compute: 4 independent row-tile chains ----
    f32x4 acc[4];
#pragma unroll
    for (int rt = 0; rt < 4; ++rt) acc[rt] = (f32x4){0.f, 0.f, 0.f, 0.f};

#pragma unroll
    for (int kc = 0; kc < 4; ++kc) {
        const int cs = ((quad + 4 * kc) ^ l16) * 8;   // (r&15)==l16 for all rt
        bf16x8 ah[4], al[4];
#pragma unroll
        for (int rt = 0; rt < 4; ++rt) {
            const int r = rt * 16 + l16;
            ah[rt] = *(const bf16x8*)&Ah[r * 128 + cs];
            al[rt] = *(const bf16x8*)&Al[r * 128 + cs];
        }
#pragma unroll
        for (int rt = 0; rt < 4; ++rt)
            acc[rt] = __builtin_amdgcn_mfma_f32_16x16x32_bf16(ah[rt], bh[kc], acc[rt], 0, 0, 0);
#pragma unroll
        for (int rt = 0; rt < 4; ++rt)
            acc[rt] = __builtin_amdgcn_mfma_f32_16x16x32_bf16(al[rt], bh[kc], acc[rt], 0, 0, 0);
#pragma unroll
        for (int rt = 0; rt < 4; ++rt)
            acc[rt] = __builtin_amdgcn_mfma_f32_16x16x32_bf16(ah[rt], bl[kc], acc[rt], 0, 0, 0);
    }

    // ---- epilogue: bias, scale, guarded store ----
    const int colg = wid * 16 + l16;
    const float bv = bias[colg];
    if (halfOut) {
        __half* oph = (__half*)out;
#pragma unroll
        for (int rt = 0; rt < 4; ++rt) {
#pragma unroll
            for (int r = 0; r < 4; ++r) {
                int rowg = m0 + rt * 16 + quad * 4 + r;
                if (rowg < n)
                    oph[(size_t)rowg * D + colg] = __float2half(acc[rt][r] + bv);
            }
        }
    } else {
        float* opf = (float*)out;
#pragma unroll
        for (int rt = 0; rt < 4; ++rt) {
#pragma unroll
            for (int r = 0; r < 4; ++r) {
                int rowg = m0 + rt * 16 + quad * 4 + r;
                if (rowg < n)
                    opf[(size_t)rowg * D + colg] = (acc[rt][r] + bv) * scale;
            }
        }
    }
}

// ---------------------------------------------------------------------------
// row_start[i] = first edge index e with row[e] >= i  (row is sorted)
// ---------------------------------------------------------------------------
__global__ void build_row_start(const int* __restrict__ row,
                                int* __restrict__ row_start, int n, int e)
{
    int i = blockIdx.x * blockDim.x + threadIdx.x;
    if (i > n) return;
    int lo = 0, hi = e;
    while (lo < hi) {
        int mid = (lo + hi) >> 1;
        if (row[mid] < i) lo = mid + 1; else hi = mid;
    }
    row_start[i] = lo;
}

// ===========================================================================
// Fused edge phase: SDDMM + segment-softmax + SPMM, one WAVE per node.
// k, v read as fp16; y written directly as bf16 hi/lo split.
// ===========================================================================
#define MAXDEG 64
#define WPB 4

__global__ __launch_bounds__(WPB * 64) void edge_attn(
    const int* __restrict__ row_start,
    const float* __restrict__ q, const __half* __restrict__ k,
    const __half* __restrict__ v, const int* __restrict__ col,
    unsigned short* __restrict__ yh, unsigned short* __restrict__ yl, int n)
{
    __shared__ float ssm[WPB][MAXDEG * H];
    __shared__ int   cm[WPB][MAXDEG];

    const int wid  = threadIdx.x >> 6;
    const int lane = threadIdx.x & 63;
    const int node = blockIdx.x * WPB + wid;
    if (node >= n) return;

    const int e0  = row_start[node];
    const int deg = row_start[node + 1] - e0;
    const int h   = lane & 3;
    const int dl  = deg < MAXDEG ? deg : MAXDEG;

    const float qa = q[(size_t)node * D + lane];
    const float qb = q[(size_t)node * D + lane + 64];

    for (int i = lane; i < dl; i += 64) cm[wid][i] = col[e0 + i];

    float m = -INFINITY, z = 0.f;
    __half kA = __float2half(0.f), kB = kA;
    if (deg > 0) {
        int c0 = cm[wid][0];
        kA = k[(size_t)c0 * D + lane];
        kB = k[(size_t)c0 * D + lane + 64];
    }
    for (int e = 0; e < deg; ++e) {
        float cA = __half2float(kA), cB = __half2float(kB);
        if (e + 1 < deg) {
            int cn = (e + 1 < MAXDEG) ? cm[wid][e + 1] : col[e0 + e + 1];
            kA = k[(size_t)cn * D + lane];
            kB = k[(size_t)cn * D + lane + 64];
        }
        float p = qa * cA + qb * cB;
        p += __shfl_xor(p, 4);
        p += __shfl_xor(p, 8);
        p += __shfl_xor(p, 16);
        p += __shfl_xor(p, 32);
        if (e < MAXDEG && lane < H) ssm[wid][e * 4 + lane] = p;
        float mn = fmaxf(m, p);
        z = z * __expf(m - mn) + __expf(p - mn);
        m = mn;
    }

    const float rz = 1.f / z;
    const int dl4 = dl * 4;
    for (int f = lane; f < dl4; f += 64)
        ssm[wid][f] = __expf(ssm[wid][f] - m) * rz;

    float acc0 = 0.f, acc1 = 0.f;
    int e = 0;
    for (; e + 4 <= dl; e += 4) {
        int c0 = cm[wid][e], c1 = cm[wid][e + 1];
        int c2 = cm[wid][e + 2], c3 = cm[wid][e + 3];
        float a0 = ssm[wid][e * 4 + h],       a1 = ssm[wid][(e + 1) * 4 + h];
        float a2 = ssm[wid][(e + 2) * 4 + h], a3 = ssm[wid][(e + 3) * 4 + h];
        const __half* v0 = v + (size_t)c0 * D;
        const __half* v1 = v + (size_t)c1 * D;
        const __half* v2 = v + (size_t)c2 * D;
        const __half* v3 = v + (size_t)c3 * D;
        float p00 = __half2float(v0[lane]),      p10 = __half2float(v1[lane]);
        float p20 = __half2float(v2[lane]),      p30 = __half2float(v3[lane]);
        float p01 = __half2float(v0[lane + 64]), p11 = __half2float(v1[lane + 64]);
        float p21 = __half2float(v2[lane + 64]), p31 = __half2float(v3[lane + 64]);
        acc0 += a0 * p00 + a1 * p10 + a2 * p20 + a3 * p30;
        acc1 += a0 * p01 + a1 * p11 + a2 * p21 + a3 * p31;
    }
    for (; e < dl; ++e) {
        int c = cm[wid][e];
        float a = ssm[wid][e * 4 + h];
        acc0 += a * __half2float(v[(size_t)c * D + lane]);
        acc1 += a * __half2float(v[(size_t)c * D + lane + 64]);
    }
    for (int e2 = MAXDEG; e2 < deg; ++e2) {
        int c = col[e0 + e2];
        const __half* kr = k + (size_t)c * D;
        float p = qa * __half2float(kr[lane]) + qb * __half2float(kr[lane + 64]);
        p += __shfl_xor(p, 4);
        p += __shfl_xor(p, 8);
        p += __shfl_xor(p, 16);
        p += __shfl_xor(p, 32);
        float a = __expf(p - m) * rz;
        acc0 += a * __half2float(v[(size_t)c * D + lane]);
        acc1 += a * __half2float(v[(size_t)c * D + lane + 64]);
    }

    unsigned short h0 = f32_to_bf16_rne(acc0);
    unsigned short h1 = f32_to_bf16_rne(acc1);
    yh[(size_t)node * D + lane]      = h0;
    yh[(size_t)node * D + lane + 64] = h1;
    yl[(size_t)node * D + lane]      = f32_to_bf16_rne(acc0 - bf16_to_f32(h0));
    yl[(size_t)node * D + lane + 64] = f32_to_bf16_rne(acc1 - bf16_to_f32(h1));
}

// ---------------------------------------------------------------------------
extern "C" void kernel_launch(void* const* d_in, const int* in_sizes, int n_in,
                              void* d_out, int out_size, void* d_ws, size_t ws_size,
                              hipStream_t stream)
{
    const float* x   = (const float*)d_in[0];
    const int*   row = (const int*)  d_in[1];
    const int*   col = (const int*)  d_in[2];
    const float* Wq  = (const float*)d_in[3];
    const float* bq  = (const float*)d_in[4];
    const float* Wk  = (const float*)d_in[5];
    const float* bk  = (const float*)d_in[6];
    const float* Wv  = (const float*)d_in[7];
    const float* bv  = (const float*)d_in[8];
    const float* Wo  = (const float*)d_in[9];
    const float* bo  = (const float*)d_in[10];
    float* out = (float*)d_out;

    const int n = in_sizes[0] / D;   // 100000
    const int e = in_sizes[1];       // 800000
    const size_t ND = (size_t)n * D;

    // Workspace (floats as unit):
    //   [0,    ND)   q  fp32
    //   [ND,  1.5ND) kh fp16
    //   [1.5ND,2ND)  vh fp16
    //   [2ND, 2.5ND) xh bf16   (aliased: yh after QKV phase)
    //   [2.5ND,3ND)  xl bf16   (aliased: yl)
    //   [3ND, ...)   wh, wl (4*D*D shorts each), row_start
    float* ws = (float*)d_ws;
    float*  q  = ws;
    __half* kh = (__half*)(ws + ND);
    __half* vh = kh + ND;
    unsigned short* xh = (unsigned short*)(ws + 2 * ND);
    unsigned short* xl = xh + ND;
    unsigned short* yh = xh;   // alias (x split dead after QKV GEMM)
    unsigned short* yl = xl;
    unsigned short* wh = (unsigned short*)(ws + 3 * ND);
    unsigned short* wl = wh + 4 * D * D;
    int* row_start = (int*)(wl + 4 * D * D);

    const int n4 = (int)(ND / 4);
    const int gx = (n + RT - 1) / RT;    // 1563

    convert_w<<<(D * D + 255) / 256, 256, 0, stream>>>(Wq, Wk, Wv, Wo, wh, wl);
    convert_split<<<(n4 + 255) / 256, 256, 0, stream>>>(x, xh, xl, n4);

    // fused QKV: sel 0 -> q fp32 (*0.5), sel 1 -> k fp16, sel 2 -> v fp16
    gemm_tile<<<dim3(gx, 3), 512, 0, stream>>>(
        xh, xl, wh, wl, bq, bk, bv,
        (void*)q, (void*)kh, (void*)vh, 0.5f, n, 0, /*halfmask=*/6);

    build_row_start<<<(n + 1 + 255) / 256, 256, 0, stream>>>(row, row_start, n, e);

    edge_attn<<<(n + WPB - 1) / WPB, WPB * 64, 0, stream>>>(
        row_start, q, kh, vh, col, yh, yl, n);

    // output projection: weight slot 3 (Wo), fp32 out
    gemm_tile<<<dim3(gx, 1), 512, 0, stream>>>(
        yh, yl, wh, wl, bo, bo, bo,
        (void*)out, (void*)out, (void*)out, 1.0f, n, 3, /*halfmask=*/0);
}